// Round 1
// baseline (39.681 us; speedup 1.0000x reference)
//
#include <hip/hip_runtime.h>

// ImplicitComplexModalFilter: K[h][l] = 2*Re[ sum_n Cm[h,n] * exp(dtA[h,n]*l) ]
// H=1024, N=64, L=2048, channels=1, n_ssm=H (rep=1).

#define Hdim 1024
#define Ndim 64
#define Ldim 2048
#define BLK  256
#define LPT  8   // l-values per thread, strided by BLK

__global__ __launch_bounds__(BLK) void icmf_kernel(
    const float* __restrict__ log_dt,
    const float* __restrict__ C_re, const float* __restrict__ C_im,
    const float* __restrict__ B_re, const float* __restrict__ B_im,
    const float* __restrict__ inv_A_real, const float* __restrict__ A_imag,
    float* __restrict__ out)
{
    __shared__ float s_cmre[Ndim], s_cmim[Ndim], s_ar2[Ndim], s_airev[Ndim],
                     s_wr[Ndim], s_wi[Ndim];
    const int h   = blockIdx.x;
    const int tid = threadIdx.x;

    if (tid < Ndim) {
        const int n   = tid;
        const int idx = h * Ndim + n;
        const float dt  = expf(log_dt[h]);
        const float Are = -expf(inv_A_real[idx]);
        const float Aim = A_imag[idx];
        const float ar  = dt * Are;          // Re(dtA)
        const float ai  = dt * Aim;          // Im(dtA)
        // scale = dt / (1 - dtA/2)
        const float dre = 1.0f - 0.5f * ar;
        const float dim = -0.5f * ai;
        const float k   = dt / (dre * dre + dim * dim);
        const float sre =  dre * k;
        const float sim = -dim * k;
        // B*C (complex)
        const float br = B_re[idx], bi = B_im[idx];
        const float cr = C_re[idx], ci = C_im[idx];
        const float bcr = br * cr - bi * ci;
        const float bci = br * ci + bi * cr;
        // Cm * 2 (fold the final 2x here)
        s_cmre[n] = 2.0f * (bcr * sre - bci * sim);
        s_cmim[n] = 2.0f * (bcr * sim + bci * sre);
        const float ar2   = ar * 1.4426950408889634f;   // log2(e)
        const float airev = ai * 0.15915494309189535f;  // 1/(2*pi), revolutions
        s_ar2[n]   = ar2;
        s_airev[n] = airev;
        // w = exp(dtA * BLK): stride-BLK advance (amplitude folded in)
        const float e  = __builtin_amdgcn_exp2f(ar2 * (float)BLK);
        const float r  = airev * (float)BLK;
        const float rf = r - floorf(r);
        s_wr[n] = e * __builtin_amdgcn_cosf(rf);
        s_wi[n] = e * __builtin_amdgcn_sinf(rf);
    }
    __syncthreads();

    float acc[LPT];
#pragma unroll
    for (int j = 0; j < LPT; ++j) acc[j] = 0.0f;

    const float l0 = (float)tid;
    for (int n = 0; n < Ndim; ++n) {
        const float cmre  = s_cmre[n];
        const float cmim  = s_cmim[n];
        const float wr    = s_wr[n];
        const float wi    = s_wi[n];
        // seed z = exp(dtA * l0)
        const float e0 = __builtin_amdgcn_exp2f(s_ar2[n] * l0);
        const float r  = s_airev[n] * l0;
        const float rf = r - floorf(r);
        float zr = e0 * __builtin_amdgcn_cosf(rf);
        float zi = e0 * __builtin_amdgcn_sinf(rf);
#pragma unroll
        for (int j = 0; j < LPT; ++j) {
            acc[j] = fmaf(cmre, zr, acc[j]);
            acc[j] = fmaf(-cmim, zi, acc[j]);
            const float nzr = zr * wr - zi * wi;   // z *= w  (advance l by BLK)
            const float nzi = zr * wi + zi * wr;
            zr = nzr; zi = nzi;
        }
    }

    float* o = out + h * Ldim + tid;
#pragma unroll
    for (int j = 0; j < LPT; ++j) o[j * BLK] = acc[j];
}

extern "C" void kernel_launch(void* const* d_in, const int* in_sizes, int n_in,
                              void* d_out, int out_size, void* d_ws, size_t ws_size,
                              hipStream_t stream) {
    // d_in order: L(scalar int), log_dt, C_re, C_im, B_re, B_im, inv_A_real, A_imag
    const float* log_dt     = (const float*)d_in[1];
    const float* C_re       = (const float*)d_in[2];
    const float* C_im       = (const float*)d_in[3];
    const float* B_re       = (const float*)d_in[4];
    const float* B_im       = (const float*)d_in[5];
    const float* inv_A_real = (const float*)d_in[6];
    const float* A_imag     = (const float*)d_in[7];
    float* out = (float*)d_out;

    icmf_kernel<<<Hdim, BLK, 0, stream>>>(log_dt, C_re, C_im, B_re, B_im,
                                          inv_A_real, A_imag, out);
}

// Round 2
// 28.979 us; speedup vs baseline: 1.3693x; 1.3693x over previous
//
#include <hip/hip_runtime.h>

// ImplicitComplexModalFilter: K[h][l] = 2*Re[ sum_n Cm[h,n] * exp(dtA[h,n]*l) ]
// H=1024, N=64, L=2048, channels=1, n_ssm=H (rep=1).
//
// Structure: 1 block per h, 256 threads, each thread owns 8 strided l-values.
// Geometric recurrence z *= w (w = exp(dtA*256)) replaces per-l transcendentals.
// Round 2: 4 independent n-chains per thread (ILP), packed float4/float2 LDS
// constants (2 vector LDS reads per n instead of 6 scalar), split accumulators.

#define Hdim 1024
#define Ndim 64
#define Ldim 2048
#define BLK  256
#define LPT  8   // l-values per thread, strided by BLK

__global__ __launch_bounds__(BLK) void icmf_kernel(
    const float* __restrict__ log_dt,
    const float* __restrict__ C_re, const float* __restrict__ C_im,
    const float* __restrict__ B_re, const float* __restrict__ B_im,
    const float* __restrict__ inv_A_real, const float* __restrict__ A_imag,
    float* __restrict__ out)
{
    __shared__ float4 s_nc[Ndim];  // {2*Cm_re, 2*Cm_im, wr, wi}
    __shared__ float2 s_rt[Ndim];  // {ar*log2e, ai/(2pi)}
    const int h   = blockIdx.x;
    const int tid = threadIdx.x;

    if (tid < Ndim) {
        const int n   = tid;
        const int idx = h * Ndim + n;
        const float dt  = expf(log_dt[h]);
        const float Are = -expf(inv_A_real[idx]);
        const float Aim = A_imag[idx];
        const float ar  = dt * Are;          // Re(dtA)
        const float ai  = dt * Aim;          // Im(dtA)
        // scale = dt / (1 - dtA/2)
        const float dre = 1.0f - 0.5f * ar;
        const float dim = -0.5f * ai;
        const float k   = dt / (dre * dre + dim * dim);
        const float sre =  dre * k;
        const float sim = -dim * k;
        // B*C (complex)
        const float br = B_re[idx], bi = B_im[idx];
        const float cr = C_re[idx], ci = C_im[idx];
        const float bcr = br * cr - bi * ci;
        const float bci = br * ci + bi * cr;
        const float cmre = 2.0f * (bcr * sre - bci * sim);
        const float cmim = 2.0f * (bcr * sim + bci * sre);
        const float ar2   = ar * 1.4426950408889634f;   // log2(e)
        const float airev = ai * 0.15915494309189535f;  // 1/(2*pi) -> revolutions
        // w = exp(dtA * BLK): stride-BLK advance
        const float e  = __builtin_amdgcn_exp2f(ar2 * (float)BLK);
        const float r  = airev * (float)BLK;
        const float rf = r - floorf(r);
        s_nc[n] = make_float4(cmre, cmim, e * __builtin_amdgcn_cosf(rf),
                                          e * __builtin_amdgcn_sinf(rf));
        s_rt[n] = make_float2(ar2, airev);
    }
    __syncthreads();

    float acca[LPT], accb[LPT];
#pragma unroll
    for (int j = 0; j < LPT; ++j) { acca[j] = 0.0f; accb[j] = 0.0f; }

    const float l0 = (float)tid;

#define SEED(rt, zr, zi)                                                  \
    {                                                                     \
        const float e0 = __builtin_amdgcn_exp2f((rt).x * l0);             \
        float f = (rt).y * l0;                                            \
        f -= floorf(f);                                                   \
        zr = e0 * __builtin_amdgcn_cosf(f);                               \
        zi = e0 * __builtin_amdgcn_sinf(f);                               \
    }

    for (int n0 = 0; n0 < Ndim; n0 += 4) {
        const float4 c0 = s_nc[n0 + 0];
        const float4 c1 = s_nc[n0 + 1];
        const float4 c2 = s_nc[n0 + 2];
        const float4 c3 = s_nc[n0 + 3];
        const float2 r0 = s_rt[n0 + 0];
        const float2 r1 = s_rt[n0 + 1];
        const float2 r2 = s_rt[n0 + 2];
        const float2 r3 = s_rt[n0 + 3];
        float zr0, zi0, zr1, zi1, zr2, zi2, zr3, zi3;
        SEED(r0, zr0, zi0);
        SEED(r1, zr1, zi1);
        SEED(r2, zr2, zi2);
        SEED(r3, zr3, zi3);
#pragma unroll
        for (int j = 0; j < LPT; ++j) {
            acca[j] = fmaf(c0.x, zr0, acca[j]);
            acca[j] = fmaf(-c0.y, zi0, acca[j]);
            accb[j] = fmaf(c1.x, zr1, accb[j]);
            accb[j] = fmaf(-c1.y, zi1, accb[j]);
            acca[j] = fmaf(c2.x, zr2, acca[j]);
            acca[j] = fmaf(-c2.y, zi2, acca[j]);
            accb[j] = fmaf(c3.x, zr3, accb[j]);
            accb[j] = fmaf(-c3.y, zi3, accb[j]);
            // advance all 4 chains: z *= w (independent dep chains -> ILP)
            float t;
            t   = fmaf(zr0, c0.z, -(zi0 * c0.w));
            zi0 = fmaf(zr0, c0.w,  zi0 * c0.z);
            zr0 = t;
            t   = fmaf(zr1, c1.z, -(zi1 * c1.w));
            zi1 = fmaf(zr1, c1.w,  zi1 * c1.z);
            zr1 = t;
            t   = fmaf(zr2, c2.z, -(zi2 * c2.w));
            zi2 = fmaf(zr2, c2.w,  zi2 * c2.z);
            zr2 = t;
            t   = fmaf(zr3, c3.z, -(zi3 * c3.w));
            zi3 = fmaf(zr3, c3.w,  zi3 * c3.z);
            zr3 = t;
        }
    }
#undef SEED

    float* o = out + h * Ldim + tid;
#pragma unroll
    for (int j = 0; j < LPT; ++j) o[j * BLK] = acca[j] + accb[j];
}

extern "C" void kernel_launch(void* const* d_in, const int* in_sizes, int n_in,
                              void* d_out, int out_size, void* d_ws, size_t ws_size,
                              hipStream_t stream) {
    // d_in order: L(scalar), log_dt, C_re, C_im, B_re, B_im, inv_A_real, A_imag
    const float* log_dt     = (const float*)d_in[1];
    const float* C_re       = (const float*)d_in[2];
    const float* C_im       = (const float*)d_in[3];
    const float* B_re       = (const float*)d_in[4];
    const float* B_im       = (const float*)d_in[5];
    const float* inv_A_real = (const float*)d_in[6];
    const float* A_imag     = (const float*)d_in[7];
    float* out = (float*)d_out;

    icmf_kernel<<<Hdim, BLK, 0, stream>>>(log_dt, C_re, C_im, B_re, B_im,
                                          inv_A_real, A_imag, out);
}

// Round 3
// 20.995 us; speedup vs baseline: 1.8900x; 1.3803x over previous
//
#include <hip/hip_runtime.h>

// ImplicitComplexModalFilter: K[h][l] = 2*Re[ sum_n Cm[h,n] * exp(dtA[h,n]*l) ]
// H=1024, N=64, L=2048, channels=1, n_ssm=H (rep=1).
//
// Round 3: replace the complex z*=w advance (6 ops/(n,l)) with the real
// 2-term recurrence y_j = p*y_{j-1} + q*y_{j-2} (p=2Re(w), q=-|w|^2), and
// pack chain PAIRS into v2f so the main loop emits v_pk_{mul,fma,add}_f32:
// 3 packed insts per 2 (n,l) elements. Seeds (exp2+sin+cos per (thread,n))
// stay scalar.

typedef float v2f __attribute__((ext_vector_type(2)));

#define Hdim 1024
#define Ndim 64
#define Ldim 2048
#define BLK  256
#define LPT  8   // l-values per thread, strided by BLK

__global__ __launch_bounds__(BLK) void icmf_kernel(
    const float* __restrict__ log_dt,
    const float* __restrict__ C_re, const float* __restrict__ C_im,
    const float* __restrict__ B_re, const float* __restrict__ B_im,
    const float* __restrict__ inv_A_real, const float* __restrict__ A_imag,
    float* __restrict__ out)
{
    __shared__ __align__(16) float4 s_seed[Ndim];  // {ar2, airev, 2*cmre, 2*cmim}
    __shared__ __align__(16) float2 s_w[Ndim];     // {wr, wi}
    __shared__ __align__(16) float  s_p[Ndim];     // 2*wr
    __shared__ __align__(16) float  s_q[Ndim];     // -(|w|^2)

    const int h   = blockIdx.x;
    const int tid = threadIdx.x;

    if (tid < Ndim) {
        const int n   = tid;
        const int idx = h * Ndim + n;
        const float dt  = expf(log_dt[h]);
        const float Are = -expf(inv_A_real[idx]);
        const float Aim = A_imag[idx];
        const float ar  = dt * Are;          // Re(dtA)  (< 0)
        const float ai  = dt * Aim;          // Im(dtA)
        // scale = dt / (1 - dtA/2)
        const float dre = 1.0f - 0.5f * ar;
        const float dim = -0.5f * ai;
        const float k   = dt / (dre * dre + dim * dim);
        const float sre =  dre * k;
        const float sim = -dim * k;
        // B*C (complex)
        const float br = B_re[idx], bi = B_im[idx];
        const float cr = C_re[idx], ci = C_im[idx];
        const float bcr = br * cr - bi * ci;
        const float bci = br * ci + bi * cr;
        const float cmre = 2.0f * (bcr * sre - bci * sim);  // fold final 2x
        const float cmim = 2.0f * (bcr * sim + bci * sre);
        const float ar2   = ar * 1.4426950408889634f;   // log2(e)
        const float airev = ai * 0.15915494309189535f;  // 1/(2*pi) -> revolutions
        // w = exp(dtA * BLK): stride-BLK advance, |w| = e <= 1
        const float e  = __builtin_amdgcn_exp2f(ar2 * (float)BLK);
        const float r  = airev * (float)BLK;
        const float rf = r - floorf(r);
        const float wr = e * __builtin_amdgcn_cosf(rf);
        const float wi = e * __builtin_amdgcn_sinf(rf);
        s_seed[n] = make_float4(ar2, airev, cmre, cmim);
        s_w[n]    = make_float2(wr, wi);
        s_p[n]    = 2.0f * wr;
        s_q[n]    = -(e * e);
    }
    __syncthreads();

    v2f acc[LPT];
#pragma unroll
    for (int j = 0; j < LPT; ++j) acc[j] = (v2f)(0.0f);

    const float l0 = (float)tid;

    for (int g = 0; g < Ndim; g += 8) {   // 8 chains = 4 packed pairs per group
        // ---- scalar seeds: y0 = Re(Cm z^l0), y1 = Re(Cm z^(l0+BLK)) ----
        float y0[8], y1[8];
#pragma unroll
        for (int k = 0; k < 8; ++k) {
            const float4 sd = s_seed[g + k];
            const float2 w  = s_w[g + k];
            const float e0 = __builtin_amdgcn_exp2f(sd.x * l0);
            float f = sd.y * l0;
            f -= floorf(f);
            const float zr = e0 * __builtin_amdgcn_cosf(f);
            const float zi = e0 * __builtin_amdgcn_sinf(f);
            const float u0r = sd.z * zr - sd.w * zi;   // Re(Cm z0)
            const float u0i = sd.z * zi + sd.w * zr;   // Im(Cm z0)
            y0[k] = u0r;
            y1[k] = u0r * w.x - u0i * w.y;             // Re(Cm z0 w)
        }
        // ---- pack pairs ----
        v2f P[4], Q[4], Y1[4], Y2[4];
#pragma unroll
        for (int p = 0; p < 4; ++p) {
            P[p] = *(const v2f*)&s_p[g + 2 * p];
            Q[p] = *(const v2f*)&s_q[g + 2 * p];
            v2f a; a.x = y0[2 * p]; a.y = y0[2 * p + 1];
            v2f b; b.x = y1[2 * p]; b.y = y1[2 * p + 1];
            Y2[p] = a; Y1[p] = b;
            acc[0] += a;
            acc[1] += b;
        }
        // ---- packed 2-term recurrence: 3 pk-ops per pair per j ----
#pragma unroll
        for (int j = 2; j < LPT; ++j) {
#pragma unroll
            for (int p = 0; p < 4; ++p) {
                const v2f t = Q[p] * Y2[p];
                const v2f y = __builtin_elementwise_fma(P[p], Y1[p], t);
                acc[j] += y;
                Y2[p] = Y1[p];
                Y1[p] = y;
            }
        }
    }

    float* o = out + h * Ldim + tid;
#pragma unroll
    for (int j = 0; j < LPT; ++j) o[j * BLK] = acc[j].x + acc[j].y;
}

extern "C" void kernel_launch(void* const* d_in, const int* in_sizes, int n_in,
                              void* d_out, int out_size, void* d_ws, size_t ws_size,
                              hipStream_t stream) {
    // d_in order: L(scalar), log_dt, C_re, C_im, B_re, B_im, inv_A_real, A_imag
    const float* log_dt     = (const float*)d_in[1];
    const float* C_re       = (const float*)d_in[2];
    const float* C_im       = (const float*)d_in[3];
    const float* B_re       = (const float*)d_in[4];
    const float* B_im       = (const float*)d_in[5];
    const float* inv_A_real = (const float*)d_in[6];
    const float* A_imag     = (const float*)d_in[7];
    float* out = (float*)d_out;

    icmf_kernel<<<Hdim, BLK, 0, stream>>>(log_dt, C_re, C_im, B_re, B_im,
                                          inv_A_real, A_imag, out);
}

// Round 4
// 15.893 us; speedup vs baseline: 2.4968x; 1.3210x over previous
//
#include <hip/hip_runtime.h>

// ImplicitComplexModalFilter: K[h][l] = 2*Re[ sum_n Cm[h,n] * exp(dtA[h,n]*l) ]
// H=1024, N=64, L=2048, channels=1, n_ssm=H (rep=1).
//
// Round 4: amortize seed transcendentals 4x. Block = 1 h, 4 waves; each wave
// owns 16 n's; each lane owns l0=lane stride 64, LPT=32. Real 2-term packed
// recurrence y_j = p*y_{j-1} + q*y_{j-2} (p=2Re(w), q=-|w|^2, w=exp(dtA*64))
// in v2f -> v_pk_{mul,fma,add}_f32. Cross-wave n-partials reduced via LDS.

typedef float v2f __attribute__((ext_vector_type(2)));

#define Hdim  1024
#define Ndim  64
#define Ldim  2048
#define BLK   256
#define LANES 64
#define LPT   32   // l-values per lane, strided by LANES
#define NPW   16   // n's per wave
#define WAVES 4

__global__ __launch_bounds__(BLK) void icmf_kernel(
    const float* __restrict__ log_dt,
    const float* __restrict__ C_re, const float* __restrict__ C_im,
    const float* __restrict__ B_re, const float* __restrict__ B_im,
    const float* __restrict__ inv_A_real, const float* __restrict__ A_imag,
    float* __restrict__ out)
{
    __shared__ __align__(16) float4 s_seed[Ndim];  // {ar2, airev, 2*cmre, 2*cmim}
    __shared__ __align__(16) float2 s_w[Ndim];     // {wr, wi}
    __shared__ __align__(16) float  s_p[Ndim];     // 2*wr
    __shared__ __align__(16) float  s_q[Ndim];     // -|w|^2
    __shared__ float s_red[WAVES][Ldim];           // 32 KB cross-wave partials

    const int h    = blockIdx.x;
    const int tid  = threadIdx.x;
    const int wave = tid >> 6;
    const int lane = tid & 63;

    if (tid < Ndim) {
        const int n   = tid;
        const int idx = h * Ndim + n;
        const float dt  = expf(log_dt[h]);
        const float Are = -expf(inv_A_real[idx]);
        const float Aim = A_imag[idx];
        const float ar  = dt * Are;          // Re(dtA) < 0
        const float ai  = dt * Aim;          // Im(dtA)
        // scale = dt / (1 - dtA/2)
        const float dre = 1.0f - 0.5f * ar;
        const float dim = -0.5f * ai;
        const float k   = dt / (dre * dre + dim * dim);
        const float sre =  dre * k;
        const float sim = -dim * k;
        // B*C (complex)
        const float br = B_re[idx], bi = B_im[idx];
        const float cr = C_re[idx], ci = C_im[idx];
        const float bcr = br * cr - bi * ci;
        const float bci = br * ci + bi * cr;
        const float cmre = 2.0f * (bcr * sre - bci * sim);  // fold final 2x
        const float cmim = 2.0f * (bcr * sim + bci * sre);
        const float ar2   = ar * 1.4426950408889634f;   // log2(e)
        const float airev = ai * 0.15915494309189535f;  // 1/(2*pi): revolutions
        // w = exp(dtA * LANES): stride-64 advance, |w| = e <= 1
        const float e  = __builtin_amdgcn_exp2f(ar2 * (float)LANES);
        const float r  = airev * (float)LANES;
        const float rf = r - floorf(r);
        const float wr = e * __builtin_amdgcn_cosf(rf);
        const float wi = e * __builtin_amdgcn_sinf(rf);
        s_seed[n] = make_float4(ar2, airev, cmre, cmim);
        s_w[n]    = make_float2(wr, wi);
        s_p[n]    = 2.0f * wr;
        s_q[n]    = -(e * e);
    }
    __syncthreads();

    v2f acc[LPT];
#pragma unroll
    for (int j = 0; j < LPT; ++j) acc[j] = (v2f)(0.0f);

    const float l0    = (float)lane;
    const int   nbase = wave * NPW;

    for (int g = 0; g < NPW; g += 4) {   // 4 chains = 2 packed pairs per group
        const int n0 = nbase + g;
        // ---- scalar seeds: y0 = Re(Cm z^l0), y1 = Re(Cm z^(l0+64)) ----
        float y0[4], y1[4];
#pragma unroll
        for (int k = 0; k < 4; ++k) {
            const float4 sd = s_seed[n0 + k];
            const float2 w  = s_w[n0 + k];
            const float e0 = __builtin_amdgcn_exp2f(sd.x * l0);
            float f = sd.y * l0;
            f -= floorf(f);
            const float zr = e0 * __builtin_amdgcn_cosf(f);
            const float zi = e0 * __builtin_amdgcn_sinf(f);
            const float u0r = sd.z * zr - sd.w * zi;   // Re(Cm z0)
            const float u0i = sd.z * zi + sd.w * zr;   // Im(Cm z0)
            y0[k] = u0r;
            y1[k] = u0r * w.x - u0i * w.y;             // Re(Cm z0 w)
        }
        // ---- pack 2 pairs ----
        const v2f P0 = *(const v2f*)&s_p[n0];
        const v2f P1 = *(const v2f*)&s_p[n0 + 2];
        const v2f Q0 = *(const v2f*)&s_q[n0];
        const v2f Q1 = *(const v2f*)&s_q[n0 + 2];
        v2f Ya2, Yb2, Ya1, Yb1;
        Ya2.x = y0[0]; Ya2.y = y0[1];
        Yb2.x = y0[2]; Yb2.y = y0[3];
        Ya1.x = y1[0]; Ya1.y = y1[1];
        Yb1.x = y1[2]; Yb1.y = y1[3];
        acc[0] += Ya2; acc[0] += Yb2;
        acc[1] += Ya1; acc[1] += Yb1;
        // ---- packed 2-term recurrence: 3 pk-ops per pair per j ----
#pragma unroll
        for (int j = 2; j < LPT; ++j) {
            const v2f t0 = Q0 * Ya2;
            const v2f ya = __builtin_elementwise_fma(P0, Ya1, t0);
            acc[j] += ya;
            Ya2 = Ya1; Ya1 = ya;
            const v2f t1 = Q1 * Yb2;
            const v2f yb = __builtin_elementwise_fma(P1, Yb1, t1);
            acc[j] += yb;
            Yb2 = Yb1; Yb1 = yb;
        }
    }

    // ---- cross-wave reduction over the 4 n-groups ----
    {
        float* dst = &s_red[wave][lane];
#pragma unroll
        for (int j = 0; j < LPT; ++j) dst[j * LANES] = acc[j].x + acc[j].y;
    }
    __syncthreads();

    float* o = out + h * Ldim;
#pragma unroll
    for (int k = 0; k < Ldim / BLK; ++k) {
        const int l = tid + k * BLK;
        o[l] = (s_red[0][l] + s_red[1][l]) + (s_red[2][l] + s_red[3][l]);
    }
}

extern "C" void kernel_launch(void* const* d_in, const int* in_sizes, int n_in,
                              void* d_out, int out_size, void* d_ws, size_t ws_size,
                              hipStream_t stream) {
    // d_in order: L(scalar), log_dt, C_re, C_im, B_re, B_im, inv_A_real, A_imag
    const float* log_dt     = (const float*)d_in[1];
    const float* C_re       = (const float*)d_in[2];
    const float* C_im       = (const float*)d_in[3];
    const float* B_re       = (const float*)d_in[4];
    const float* B_im       = (const float*)d_in[5];
    const float* inv_A_real = (const float*)d_in[6];
    const float* A_imag     = (const float*)d_in[7];
    float* out = (float*)d_out;

    icmf_kernel<<<Hdim, BLK, 0, stream>>>(log_dt, C_re, C_im, B_re, B_im,
                                          inv_A_real, A_imag, out);
}